// Round 2
// baseline (733.408 us; speedup 1.0000x reference)
//
#include <hip/hip_runtime.h>

#define N_NODES_C 50000

// ---------------------------------------------------------------------------
// Detect whether edge_index arrived as int64 (every odd 32-bit word == 0 for
// non-negative values) or int32. All writers store 0 -> benign race.
// ---------------------------------------------------------------------------
__global__ void detect_kernel(const int* __restrict__ w, int ncheck, int* __restrict__ flag) {
    int tid = blockIdx.x * blockDim.x + threadIdx.x;
    if (tid < ncheck) {
        if (w[2 * tid + 1] != 0) *flag = 0;   // found nonzero odd word -> int32
    }
}

// counts[dst]++ over all edges
__global__ void count_kernel(const int* __restrict__ ei, int E, const int* __restrict__ flag,
                             int* __restrict__ counts) {
    int e = blockIdx.x * blockDim.x + threadIdx.x;
    if (e >= E) return;
    int shift = (*flag != 0) ? 1 : 0;
    int d = ei[(unsigned)(E + e) << shift];
    atomicAdd(&counts[d], 1);
}

// dis = rsqrt(indegree + 1)
__global__ void dis_kernel(const int* __restrict__ counts, float* __restrict__ dis, int n) {
    int i = blockIdx.x * blockDim.x + threadIdx.x;
    if (i < n) dis[i] = rsqrtf((float)counts[i] + 1.0f);
}

// Single-block exclusive scan of counts -> row_start (and cursor copy).
__global__ void scan_kernel(const int* __restrict__ counts, int* __restrict__ row_start,
                            int* __restrict__ cursor, int n) {
    __shared__ int wsum[16];
    __shared__ int carry;
    __shared__ int chunk_total;
    int tid = threadIdx.x;
    int lane = tid & 63;
    int wid = tid >> 6;
    if (tid == 0) carry = 0;
    __syncthreads();
    for (int base = 0; base < n; base += 1024) {
        int i = base + tid;
        int v = (i < n) ? counts[i] : 0;
        int x = v;
        #pragma unroll
        for (int off = 1; off < 64; off <<= 1) {
            int y = __shfl_up(x, off);
            if (lane >= off) x += y;
        }
        if (lane == 63) wsum[wid] = x;
        __syncthreads();
        if (tid == 0) {
            int run = 0;
            #pragma unroll
            for (int q = 0; q < 16; q++) { int t = wsum[q]; wsum[q] = run; run += t; }
            chunk_total = run;
        }
        __syncthreads();
        int excl = x - v + wsum[wid] + carry;
        if (i < n) { row_start[i] = excl; cursor[i] = excl; }
        __syncthreads();
        if (tid == 0) carry += chunk_total;
        __syncthreads();
    }
    if (tid == 0) row_start[n] = carry;
}

// Scatter edges into CSR; precompute per-edge weight dis[src]*dis[dst]
__global__ void fill_kernel(const int* __restrict__ ei, int E, const int* __restrict__ flag,
                            const float* __restrict__ dis, int* __restrict__ cursor,
                            int* __restrict__ csr_src, float* __restrict__ csr_w) {
    int e = blockIdx.x * blockDim.x + threadIdx.x;
    if (e >= E) return;
    int shift = (*flag != 0) ? 1 : 0;
    int s = ei[(unsigned)e << shift];
    int d = ei[(unsigned)(E + e) << shift];
    int pos = atomicAdd(&cursor[d], 1);
    csr_src[pos] = s;
    csr_w[pos] = dis[s] * dis[d];
}

// ---------------------------------------------------------------------------
// GEMM: Y[:, ycol0:ycol0+N] = X @ W   (X: [M,K] with row stride ldx, W: [K,N])
// Block: 256 threads, 32 rows/block; W and padded X tile staged in LDS.
// ---------------------------------------------------------------------------
template <int K, int N>
__global__ __launch_bounds__(256) void gemm_kernel(const float* __restrict__ X, int ldx,
                                                   const float* __restrict__ W,
                                                   float* __restrict__ Y, int ldy, int ycol0,
                                                   int M) {
    constexpr int BM = 32;
    constexpr int XLD = K + 4;                 // pad to spread LDS banks
    __shared__ alignas(16) float xs[BM * XLD];
    __shared__ alignas(16) float ws[K * N];
    int t = threadIdx.x;
    int row0 = blockIdx.x * BM;

    // stage W (full matrix) via float4
    constexpr int WF4 = K * N / 4;
    const float4* W4 = (const float4*)W;
    for (int i = t; i < WF4; i += 256) {
        *(float4*)&ws[i * 4] = W4[i];
    }
    // stage X tile via float4, zero-fill out-of-range rows
    constexpr int KQ = K / 4;
    for (int i = t; i < BM * KQ; i += 256) {
        int r = i / KQ, kq = i % KQ;
        float4 v = make_float4(0.f, 0.f, 0.f, 0.f);
        if (row0 + r < M) v = *(const float4*)&X[(size_t)(row0 + r) * ldx + 4 * kq];
        *(float4*)&xs[r * XLD + 4 * kq] = v;
    }
    __syncthreads();

    int r = t >> 3;          // 0..31
    int cl = t & 7;          // 0..7
    float acc[N / 8];
    #pragma unroll
    for (int j = 0; j < N / 8; j++) acc[j] = 0.f;

    #pragma unroll 4
    for (int k = 0; k < K; k++) {
        float xv = xs[r * XLD + k];
        #pragma unroll
        for (int j = 0; j < N / 8; j++)
            acc[j] = fmaf(xv, ws[k * N + cl + 8 * j], acc[j]);
    }

    int row = row0 + r;
    if (row < M) {
        float* yp = Y + (size_t)row * ldy + ycol0 + cl;
        #pragma unroll
        for (int j = 0; j < N / 8; j++) yp[8 * j] = acc[j];
    }
}

// ---------------------------------------------------------------------------
// Aggregation: out[n,:] = relu( sum_{e in CSR[n]} w_e * h[src_e,:]
//                               + dis[n]^2 * h[n,:] + bias )
// One wave per node; DCAT = concatenated feature dim (mu | log).
// ---------------------------------------------------------------------------
template <int DCAT, bool FINAL>
__global__ __launch_bounds__(256) void agg_kernel(const float* __restrict__ h,
                                                  const int* __restrict__ row_start,
                                                  const int* __restrict__ csr_src,
                                                  const float* __restrict__ csr_w,
                                                  const float* __restrict__ dis,
                                                  const float* __restrict__ bmu,
                                                  const float* __restrict__ blog,
                                                  float* __restrict__ out,
                                                  float* __restrict__ outlog, int M) {
    constexpr int CH = DCAT / 64;      // floats per lane (2 or 4)
    int wid = threadIdx.x >> 6;
    int lane = threadIdx.x & 63;
    int node = blockIdx.x * 4 + wid;
    if (node >= M) return;
    int c0 = lane * CH;

    float acc[CH];
    float dn = dis[node];
    float sw = dn * dn;
    {
        const float* hp = h + (size_t)node * DCAT + c0;
        if constexpr (CH == 4) {
            float4 v = *(const float4*)hp;
            acc[0] = sw * v.x; acc[1] = sw * v.y; acc[2] = sw * v.z; acc[3] = sw * v.w;
        } else {
            float2 v = *(const float2*)hp;
            acc[0] = sw * v.x; acc[1] = sw * v.y;
        }
    }
    int s = row_start[node];
    int e = row_start[node + 1];
    for (int i = s; i < e; ++i) {
        int src = csr_src[i];
        float w = csr_w[i];
        const float* hp = h + (size_t)src * DCAT + c0;
        if constexpr (CH == 4) {
            float4 v = *(const float4*)hp;
            acc[0] = fmaf(w, v.x, acc[0]);
            acc[1] = fmaf(w, v.y, acc[1]);
            acc[2] = fmaf(w, v.z, acc[2]);
            acc[3] = fmaf(w, v.w, acc[3]);
        } else {
            float2 v = *(const float2*)hp;
            acc[0] = fmaf(w, v.x, acc[0]);
            acc[1] = fmaf(w, v.y, acc[1]);
        }
    }
    constexpr int D = DCAT / 2;
    #pragma unroll
    for (int u = 0; u < CH; u++) {
        int c = c0 + u;
        float b = (c < D) ? bmu[c] : blog[c - D];
        float v = fmaxf(acc[u] + b, 0.0f);
        if constexpr (FINAL) {
            if (c < D) out[(size_t)node * D + c] = v;
            else       outlog[(size_t)node * D + (c - D)] = v;
        } else {
            out[(size_t)node * DCAT + c] = v;
        }
    }
}

extern "C" void kernel_launch(void* const* d_in, const int* in_sizes, int n_in,
                              void* d_out, int out_size, void* d_ws, size_t ws_size,
                              hipStream_t stream) {
    const float* x   = (const float*)d_in[0];
    const int*   ei  = (const int*)d_in[1];
    const float* Wm1 = (const float*)d_in[2];  const float* bm1 = (const float*)d_in[3];
    const float* Wm2 = (const float*)d_in[4];  const float* bm2 = (const float*)d_in[5];
    const float* Wm3 = (const float*)d_in[6];  const float* bm3 = (const float*)d_in[7];
    const float* Wl1 = (const float*)d_in[8];  const float* bl1 = (const float*)d_in[9];
    const float* Wl2 = (const float*)d_in[10]; const float* bl2 = (const float*)d_in[11];
    const float* Wl3 = (const float*)d_in[12]; const float* bl3 = (const float*)d_in[13];
    float* out = (float*)d_out;

    const int M = N_NODES_C;
    const int E = in_sizes[1] / 2;

    char* ws = (char*)d_ws;
    size_t off = 0;
    auto alloc = [&](size_t bytes) {
        size_t o = off;
        off += (bytes + 255) & ~(size_t)255;
        return o;
    };
    int*   flag      = (int*)(ws + alloc(4));
    int*   counts    = (int*)(ws + alloc((size_t)M * 4));
    int*   row_start = (int*)(ws + alloc((size_t)(M + 1) * 4));
    int*   cursor    = (int*)(ws + alloc((size_t)M * 4));
    float* dis       = (float*)(ws + alloc((size_t)M * 4));
    int*   csr_src   = (int*)(ws + alloc((size_t)E * 4));
    float* csr_w     = (float*)(ws + alloc((size_t)E * 4));
    float* bufA      = (float*)(ws + alloc((size_t)M * 256 * 4));
    float* bufB      = (float*)(ws + alloc((size_t)M * 256 * 4));

    hipMemsetAsync(flag, 1, 4, stream);                 // assume int64 until disproven
    hipMemsetAsync(counts, 0, (size_t)M * 4, stream);

    int ncheck = (E < 2048) ? E : 2048;
    detect_kernel<<<(ncheck + 255) / 256, 256, 0, stream>>>(ei, ncheck, flag);
    count_kernel<<<(E + 255) / 256, 256, 0, stream>>>(ei, E, flag, counts);
    dis_kernel<<<(M + 255) / 256, 256, 0, stream>>>(counts, dis, M);
    scan_kernel<<<1, 1024, 0, stream>>>(counts, row_start, cursor, M);
    fill_kernel<<<(E + 255) / 256, 256, 0, stream>>>(ei, E, flag, dis, cursor, csr_src, csr_w);

    int gblocks = (M + 31) / 32;
    int ablocks = (M + 3) / 4;

    // ---- layer 1: x[50000,128] -> h[50000, 64|64] -> agg+relu ----
    gemm_kernel<128, 64><<<gblocks, 256, 0, stream>>>(x, 128, Wm1, bufA, 128, 0, M);
    gemm_kernel<128, 64><<<gblocks, 256, 0, stream>>>(x, 128, Wl1, bufA, 128, 64, M);
    agg_kernel<128, false><<<ablocks, 256, 0, stream>>>(bufA, row_start, csr_src, csr_w, dis,
                                                        bm1, bl1, bufB, nullptr, M);

    // ---- layer 2: [50000, 64|64] -> h[50000, 128|128] -> agg+relu ----
    gemm_kernel<64, 128><<<gblocks, 256, 0, stream>>>(bufB, 128, Wm2, bufA, 256, 0, M);
    gemm_kernel<64, 128><<<gblocks, 256, 0, stream>>>(bufB + 64, 128, Wl2, bufA, 256, 128, M);
    agg_kernel<256, false><<<ablocks, 256, 0, stream>>>(bufA, row_start, csr_src, csr_w, dis,
                                                        bm2, bl2, bufB, nullptr, M);

    // ---- layer 3: [50000, 128|128] -> h[50000, 64|64] -> agg+relu -> out ----
    gemm_kernel<128, 64><<<gblocks, 256, 0, stream>>>(bufB, 256, Wm3, bufA, 128, 0, M);
    gemm_kernel<128, 64><<<gblocks, 256, 0, stream>>>(bufB + 128, 256, Wl3, bufA, 128, 64, M);
    agg_kernel<128, true><<<ablocks, 256, 0, stream>>>(bufA, row_start, csr_src, csr_w, dis,
                                                       bm3, bl3, out, out + (size_t)M * 64, M);
}

// Round 4
// 520.566 us; speedup vs baseline: 1.4089x; 1.4089x over previous
//
#include <hip/hip_runtime.h>

#define N_NODES_C 50000

// ---------------------------------------------------------------------------
// Detect whether edge_index arrived as int64 (every odd 32-bit word == 0 for
// non-negative values) or int32. All writers store 0 -> benign race.
// ---------------------------------------------------------------------------
__global__ void detect_kernel(const int* __restrict__ w, int ncheck, int* __restrict__ flag) {
    int tid = blockIdx.x * blockDim.x + threadIdx.x;
    if (tid < ncheck) {
        if (w[2 * tid + 1] != 0) *flag = 0;   // found nonzero odd word -> int32
    }
}

// counts[dst]++ over all edges
__global__ void count_kernel(const int* __restrict__ ei, int E, const int* __restrict__ flag,
                             int* __restrict__ counts) {
    int e = blockIdx.x * blockDim.x + threadIdx.x;
    if (e >= E) return;
    int shift = (*flag != 0) ? 1 : 0;
    int d = ei[(unsigned)(E + e) << shift];
    atomicAdd(&counts[d], 1);
}

// dis = rsqrt(indegree + 1)
__global__ void dis_kernel(const int* __restrict__ counts, float* __restrict__ dis, int n) {
    int i = blockIdx.x * blockDim.x + threadIdx.x;
    if (i < n) dis[i] = rsqrtf((float)counts[i] + 1.0f);
}

// Single-block exclusive scan of counts -> row_start (and cursor copy).
__global__ void scan_kernel(const int* __restrict__ counts, int* __restrict__ row_start,
                            int* __restrict__ cursor, int n) {
    __shared__ int wsum[16];
    __shared__ int carry;
    __shared__ int chunk_total;
    int tid = threadIdx.x;
    int lane = tid & 63;
    int wid = tid >> 6;
    if (tid == 0) carry = 0;
    __syncthreads();
    for (int base = 0; base < n; base += 1024) {
        int i = base + tid;
        int v = (i < n) ? counts[i] : 0;
        int x = v;
        #pragma unroll
        for (int off = 1; off < 64; off <<= 1) {
            int y = __shfl_up(x, off);
            if (lane >= off) x += y;
        }
        if (lane == 63) wsum[wid] = x;
        __syncthreads();
        if (tid == 0) {
            int run = 0;
            #pragma unroll
            for (int q = 0; q < 16; q++) { int t = wsum[q]; wsum[q] = run; run += t; }
            chunk_total = run;
        }
        __syncthreads();
        int excl = x - v + wsum[wid] + carry;
        if (i < n) { row_start[i] = excl; cursor[i] = excl; }
        __syncthreads();
        if (tid == 0) carry += chunk_total;
        __syncthreads();
    }
    if (tid == 0) row_start[n] = carry;
}

// Scatter edges into CSR; precompute per-edge weight dis[src]*dis[dst]
__global__ void fill_kernel(const int* __restrict__ ei, int E, const int* __restrict__ flag,
                            const float* __restrict__ dis, int* __restrict__ cursor,
                            int* __restrict__ csr_src, float* __restrict__ csr_w) {
    int e = blockIdx.x * blockDim.x + threadIdx.x;
    if (e >= E) return;
    int shift = (*flag != 0) ? 1 : 0;
    int s = ei[(unsigned)e << shift];
    int d = ei[(unsigned)(E + e) << shift];
    int pos = atomicAdd(&cursor[d], 1);
    csr_src[pos] = s;
    csr_w[pos] = dis[s] * dis[d];
}

// ---------------------------------------------------------------------------
// Aggregation over 128-wide rows: out[n,:] = sum_e w_e*h[src_e,:] + dis[n]^2*h[n,:]
// One wave per node. Half-wave (32 lanes x float4) per edge; 2 edges per wave
// concurrently, unrolled x2 -> 4 gathers in flight. FINAL adds bias+relu and
// splits mu|log into two outputs.
// ---------------------------------------------------------------------------
template <bool FINAL>
__global__ __launch_bounds__(256) void agg128_kernel(const float* __restrict__ h,
                                                     const int* __restrict__ row_start,
                                                     const int* __restrict__ csr_src,
                                                     const float* __restrict__ csr_w,
                                                     const float* __restrict__ dis,
                                                     const float* __restrict__ bmu,
                                                     const float* __restrict__ blog,
                                                     float* __restrict__ out,
                                                     float* __restrict__ outlog, int M) {
    int wid = threadIdx.x >> 6;
    int lane = threadIdx.x & 63;
    int node = blockIdx.x * 4 + wid;
    if (node >= M) return;
    int half = lane >> 5;
    int c0 = (lane & 31) * 4;

    int s = row_start[node];
    int e = row_start[node + 1];

    float a0 = 0.f, a1 = 0.f, a2 = 0.f, a3 = 0.f;
    int i = s + half;
    for (; i + 2 < e; i += 4) {
        int s0 = csr_src[i];
        int s1 = csr_src[i + 2];
        float w0 = csr_w[i];
        float w1 = csr_w[i + 2];
        float4 v0 = *(const float4*)&h[(size_t)s0 * 128 + c0];
        float4 v1 = *(const float4*)&h[(size_t)s1 * 128 + c0];
        a0 = fmaf(w0, v0.x, a0); a1 = fmaf(w0, v0.y, a1);
        a2 = fmaf(w0, v0.z, a2); a3 = fmaf(w0, v0.w, a3);
        a0 = fmaf(w1, v1.x, a0); a1 = fmaf(w1, v1.y, a1);
        a2 = fmaf(w1, v1.z, a2); a3 = fmaf(w1, v1.w, a3);
    }
    if (i < e) {
        int s0 = csr_src[i];
        float w0 = csr_w[i];
        float4 v0 = *(const float4*)&h[(size_t)s0 * 128 + c0];
        a0 = fmaf(w0, v0.x, a0); a1 = fmaf(w0, v0.y, a1);
        a2 = fmaf(w0, v0.z, a2); a3 = fmaf(w0, v0.w, a3);
    }
    // combine the two half-wave partial sums (lane <-> lane^32)
    a0 += __shfl_xor(a0, 32);
    a1 += __shfl_xor(a1, 32);
    a2 += __shfl_xor(a2, 32);
    a3 += __shfl_xor(a3, 32);

    // self-loop term (added once, after combine)
    float dn = dis[node];
    float sw = dn * dn;
    float4 sv = *(const float4*)&h[(size_t)node * 128 + c0];
    a0 = fmaf(sw, sv.x, a0); a1 = fmaf(sw, sv.y, a1);
    a2 = fmaf(sw, sv.z, a2); a3 = fmaf(sw, sv.w, a3);

    if (half == 0) {
        if constexpr (FINAL) {
            float b0, b1, b2, b3;
            float* yp;
            if (c0 < 64) {
                b0 = bmu[c0]; b1 = bmu[c0 + 1]; b2 = bmu[c0 + 2]; b3 = bmu[c0 + 3];
                yp = out + (size_t)node * 64 + c0;
            } else {
                int c = c0 - 64;
                b0 = blog[c]; b1 = blog[c + 1]; b2 = blog[c + 2]; b3 = blog[c + 3];
                yp = outlog + (size_t)node * 64 + c;
            }
            float4 o;
            o.x = fmaxf(a0 + b0, 0.f);
            o.y = fmaxf(a1 + b1, 0.f);
            o.z = fmaxf(a2 + b2, 0.f);
            o.w = fmaxf(a3 + b3, 0.f);
            *(float4*)yp = o;
        } else {
            *(float4*)&out[(size_t)node * 128 + c0] = make_float4(a0, a1, a2, a3);
        }
    }
}

// ---------------------------------------------------------------------------
// GEMM: Y[:, 0:N] = act(X[:, 0:K] @ W + b)   (X row stride ldx, Y row stride ldy)
// CAT: W is two [K, N/2] matrices (Wa|Wb) side by side, biases ba|bb.
// Micro-tile: 256 threads, 32 rows/block, each thread RPT rows x 4 cols.
// W staged in K-chunks of <=64 to fit LDS.
// ---------------------------------------------------------------------------
template <int K, int N, bool CAT, bool RELU, bool BIAS>
__global__ __launch_bounds__(256) void gemm_kernel(const float* __restrict__ X, int ldx,
                                                   const float* __restrict__ Wa,
                                                   const float* __restrict__ Wb,
                                                   const float* __restrict__ ba,
                                                   const float* __restrict__ bb,
                                                   float* __restrict__ Y, int ldy, int M) {
    constexpr int BM = 32;
    constexpr int KCH = (K > 64) ? 64 : K;
    constexpr int XLD = K + 4;
    constexpr int NTX = N / 4;          // threads across cols
    constexpr int NTY = 256 / NTX;      // thread groups down rows
    constexpr int RPT = BM / NTY;       // rows per thread
    __shared__ alignas(16) float xs[BM * XLD];
    __shared__ alignas(16) float ws[KCH * N];

    int t = threadIdx.x;
    int row0 = blockIdx.x * BM;

    // stage X tile (float4, zero-fill OOB rows)
    constexpr int KQ = K / 4;
    for (int i = t; i < BM * KQ; i += 256) {
        int r = i / KQ, kq = i % KQ;
        float4 v = make_float4(0.f, 0.f, 0.f, 0.f);
        if (row0 + r < M) v = *(const float4*)&X[(size_t)(row0 + r) * ldx + 4 * kq];
        *(float4*)&xs[r * XLD + 4 * kq] = v;
    }

    int tx = t % NTX;
    int ty = t / NTX;
    float acc[RPT][4];
    #pragma unroll
    for (int rr = 0; rr < RPT; rr++)
        #pragma unroll
        for (int j = 0; j < 4; j++) acc[rr][j] = 0.f;

    for (int kc = 0; kc < K; kc += KCH) {
        __syncthreads();   // X ready (first iter) / ws safe to overwrite (later)
        constexpr int NQ = N / 4;
        if constexpr (CAT) {
            constexpr int HQ = (N / 2) / 4;
            for (int i = t; i < KCH * NQ; i += 256) {
                int kk = i / NQ, cq = i % NQ;
                float4 v;
                if (cq < HQ) v = *(const float4*)&Wa[(size_t)(kc + kk) * (N / 2) + 4 * cq];
                else         v = *(const float4*)&Wb[(size_t)(kc + kk) * (N / 2) + 4 * (cq - HQ)];
                *(float4*)&ws[kk * N + 4 * cq] = v;
            }
        } else {
            for (int i = t; i < KCH * NQ; i += 256) {
                int kk = i / NQ, cq = i % NQ;
                *(float4*)&ws[kk * N + 4 * cq] =
                    *(const float4*)&Wa[(size_t)(kc + kk) * N + 4 * cq];
            }
        }
        __syncthreads();

        #pragma unroll 4
        for (int kk = 0; kk < KCH; ++kk) {
            int k = kc + kk;
            float4 wv = *(const float4*)&ws[kk * N + tx * 4];
            float xv[RPT];
            #pragma unroll
            for (int rr = 0; rr < RPT; rr++) xv[rr] = xs[(ty * RPT + rr) * XLD + k];
            #pragma unroll
            for (int rr = 0; rr < RPT; rr++) {
                acc[rr][0] = fmaf(xv[rr], wv.x, acc[rr][0]);
                acc[rr][1] = fmaf(xv[rr], wv.y, acc[rr][1]);
                acc[rr][2] = fmaf(xv[rr], wv.z, acc[rr][2]);
                acc[rr][3] = fmaf(xv[rr], wv.w, acc[rr][3]);
            }
        }
    }

    // epilogue
    int c0 = tx * 4;
    float b0 = 0.f, b1 = 0.f, b2 = 0.f, b3 = 0.f;
    if constexpr (BIAS) {
        if constexpr (CAT) {
            if (c0 < N / 2) { b0 = ba[c0]; b1 = ba[c0 + 1]; b2 = ba[c0 + 2]; b3 = ba[c0 + 3]; }
            else {
                int c = c0 - N / 2;
                b0 = bb[c]; b1 = bb[c + 1]; b2 = bb[c + 2]; b3 = bb[c + 3];
            }
        } else {
            b0 = ba[c0]; b1 = ba[c0 + 1]; b2 = ba[c0 + 2]; b3 = ba[c0 + 3];
        }
    }
    #pragma unroll
    for (int rr = 0; rr < RPT; rr++) {
        int row = row0 + ty * RPT + rr;
        if (row < M) {
            float4 o;
            o.x = acc[rr][0] + b0;
            o.y = acc[rr][1] + b1;
            o.z = acc[rr][2] + b2;
            o.w = acc[rr][3] + b3;
            if constexpr (RELU) {
                o.x = fmaxf(o.x, 0.f); o.y = fmaxf(o.y, 0.f);
                o.z = fmaxf(o.z, 0.f); o.w = fmaxf(o.w, 0.f);
            }
            *(float4*)&Y[(size_t)row * ldy + c0] = o;
        }
    }
}

extern "C" void kernel_launch(void* const* d_in, const int* in_sizes, int n_in,
                              void* d_out, int out_size, void* d_ws, size_t ws_size,
                              hipStream_t stream) {
    const float* x   = (const float*)d_in[0];
    const int*   ei  = (const int*)d_in[1];
    const float* Wm1 = (const float*)d_in[2];  const float* bm1 = (const float*)d_in[3];
    const float* Wm2 = (const float*)d_in[4];  const float* bm2 = (const float*)d_in[5];
    const float* Wm3 = (const float*)d_in[6];  const float* bm3 = (const float*)d_in[7];
    const float* Wl1 = (const float*)d_in[8];  const float* bl1 = (const float*)d_in[9];
    const float* Wl2 = (const float*)d_in[10]; const float* bl2 = (const float*)d_in[11];
    const float* Wl3 = (const float*)d_in[12]; const float* bl3 = (const float*)d_in[13];
    float* out = (float*)d_out;

    const int M = N_NODES_C;
    const int E = in_sizes[1] / 2;

    char* ws = (char*)d_ws;
    size_t off = 0;
    auto alloc = [&](size_t bytes) {
        size_t o = off;
        off += (bytes + 255) & ~(size_t)255;
        return o;
    };
    int*   flag      = (int*)(ws + alloc(4));
    int*   counts    = (int*)(ws + alloc((size_t)M * 4));
    int*   row_start = (int*)(ws + alloc((size_t)(M + 1) * 4));
    int*   cursor    = (int*)(ws + alloc((size_t)M * 4));
    float* dis       = (float*)(ws + alloc((size_t)M * 4));
    int*   csr_src   = (int*)(ws + alloc((size_t)E * 4));
    float* csr_w     = (float*)(ws + alloc((size_t)E * 4));
    float* bufA      = (float*)(ws + alloc((size_t)M * 256 * 4));
    float* bufB      = (float*)(ws + alloc((size_t)M * 256 * 4));

    hipMemsetAsync(flag, 1, 4, stream);                 // nonzero -> assume int64
    hipMemsetAsync(counts, 0, (size_t)M * 4, stream);

    int ncheck = (E < 2048) ? E : 2048;
    detect_kernel<<<(ncheck + 255) / 256, 256, 0, stream>>>(ei, ncheck, flag);
    count_kernel<<<(E + 255) / 256, 256, 0, stream>>>(ei, E, flag, counts);
    dis_kernel<<<(M + 255) / 256, 256, 0, stream>>>(counts, dis, M);
    scan_kernel<<<1, 1024, 0, stream>>>(counts, row_start, cursor, M);
    fill_kernel<<<(E + 255) / 256, 256, 0, stream>>>(ei, E, flag, dis, cursor, csr_src, csr_w);

    int gblocks = (M + 31) / 32;
    int ablocks = (M + 3) / 4;

    // aggX = A_hat @ x  (pure linear)            x[50000,128] -> bufA[:,0:128]
    agg128_kernel<false><<<ablocks, 256, 0, stream>>>(x, row_start, csr_src, csr_w, dis,
                                                      nullptr, nullptr, bufA, nullptr, M);
    // layer 1: h1 = relu(aggX @ [Wm1|Wl1] + [bm1|bl1])  -> bufB[:,0:128] (mu|log)
    gemm_kernel<128, 128, true, true, true><<<gblocks, 256, 0, stream>>>(
        bufA, 128, Wm1, Wl1, bm1, bl1, bufB, 128, M);

    // aggB = A_hat @ h1 (pure)                   bufB[:,0:128] -> bufA[:,0:128]
    agg128_kernel<false><<<ablocks, 256, 0, stream>>>(bufB, row_start, csr_src, csr_w, dis,
                                                      nullptr, nullptr, bufA, nullptr, M);
    // layer 2: h2_mu = relu(aggB[:,0:64] @ Wm2 + bm2) -> bufB[:,0:128]
    //          h2_log = relu(aggB[:,64:128] @ Wl2 + bl2) -> bufB[:,128:256]
    gemm_kernel<64, 128, false, true, true><<<gblocks, 256, 0, stream>>>(
        bufA, 128, Wm2, nullptr, bm2, nullptr, bufB, 256, M);
    gemm_kernel<64, 128, false, true, true><<<gblocks, 256, 0, stream>>>(
        bufA + 64, 128, Wl2, nullptr, bl2, nullptr, bufB + 128, 256, M);

    // layer 3 GEMMs (no bias/relu yet): g = h2 @ W3 -> bufA[:,0:128] (mu|log)
    gemm_kernel<128, 64, false, false, false><<<gblocks, 256, 0, stream>>>(
        bufB, 256, Wm3, nullptr, nullptr, nullptr, bufA, 128, M);
    gemm_kernel<128, 64, false, false, false><<<gblocks, 256, 0, stream>>>(
        bufB + 128, 256, Wl3, nullptr, nullptr, nullptr, bufA + 64, 128, M);

    // final aggregation + bias + relu, split mu|log into d_out
    agg128_kernel<true><<<ablocks, 256, 0, stream>>>(bufA, row_start, csr_src, csr_w, dis,
                                                     bm3, bl3, out, out + (size_t)M * 64, M);
}

// Round 6
// 520.154 us; speedup vs baseline: 1.4100x; 1.0008x over previous
//
#include <hip/hip_runtime.h>

#define N_NODES_C 50000

// ---------------------------------------------------------------------------
// Detect whether edge_index arrived as int64 (every odd 32-bit word == 0 for
// non-negative values) or int32. All writers store 0 -> benign race.
// ---------------------------------------------------------------------------
__global__ void detect_kernel(const int* __restrict__ w, int ncheck, int* __restrict__ flag) {
    int tid = blockIdx.x * blockDim.x + threadIdx.x;
    if (tid < ncheck) {
        if (w[2 * tid + 1] != 0) *flag = 0;   // found nonzero odd word -> int32
    }
}

// counts[dst]++ over all edges
__global__ void count_kernel(const int* __restrict__ ei, int E, const int* __restrict__ flag,
                             int* __restrict__ counts) {
    int e = blockIdx.x * blockDim.x + threadIdx.x;
    if (e >= E) return;
    int shift = (*flag != 0) ? 1 : 0;
    int d = ei[(unsigned)(E + e) << shift];
    atomicAdd(&counts[d], 1);
}

// dis = rsqrt(indegree + 1)
__global__ void dis_kernel(const int* __restrict__ counts, float* __restrict__ dis, int n) {
    int i = blockIdx.x * blockDim.x + threadIdx.x;
    if (i < n) dis[i] = rsqrtf((float)counts[i] + 1.0f);
}

// Single-block exclusive scan of counts -> row_start (and cursor copy).
__global__ void scan_kernel(const int* __restrict__ counts, int* __restrict__ row_start,
                            int* __restrict__ cursor, int n) {
    __shared__ int wsum[16];
    __shared__ int carry;
    __shared__ int chunk_total;
    int tid = threadIdx.x;
    int lane = tid & 63;
    int wid = tid >> 6;
    if (tid == 0) carry = 0;
    __syncthreads();
    for (int base = 0; base < n; base += 1024) {
        int i = base + tid;
        int v = (i < n) ? counts[i] : 0;
        int x = v;
        #pragma unroll
        for (int off = 1; off < 64; off <<= 1) {
            int y = __shfl_up(x, off);
            if (lane >= off) x += y;
        }
        if (lane == 63) wsum[wid] = x;
        __syncthreads();
        if (tid == 0) {
            int run = 0;
            #pragma unroll
            for (int q = 0; q < 16; q++) { int t = wsum[q]; wsum[q] = run; run += t; }
            chunk_total = run;
        }
        __syncthreads();
        int excl = x - v + wsum[wid] + carry;
        if (i < n) { row_start[i] = excl; cursor[i] = excl; }
        __syncthreads();
        if (tid == 0) carry += chunk_total;
        __syncthreads();
    }
    if (tid == 0) row_start[n] = carry;
}

// Scatter edges into CSR; precompute per-edge weight dis[src]*dis[dst]
__global__ void fill_kernel(const int* __restrict__ ei, int E, const int* __restrict__ flag,
                            const float* __restrict__ dis, int* __restrict__ cursor,
                            int* __restrict__ csr_src, float* __restrict__ csr_w) {
    int e = blockIdx.x * blockDim.x + threadIdx.x;
    if (e >= E) return;
    int shift = (*flag != 0) ? 1 : 0;
    int s = ei[(unsigned)e << shift];
    int d = ei[(unsigned)(E + e) << shift];
    int pos = atomicAdd(&cursor[d], 1);
    csr_src[pos] = s;
    csr_w[pos] = dis[s] * dis[d];
}

// ---------------------------------------------------------------------------
// Aggregation over 128-wide rows: out[n,:] = sum_e w_e*h[src_e,:] + dis[n]^2*h[n,:]
// One wave per node. Half-wave (32 lanes x float4) per edge; 2 edges per wave
// concurrently, unrolled x2 -> 4 gathers in flight. FINAL adds bias+relu and
// splits mu|log into two outputs.
// ---------------------------------------------------------------------------
template <bool FINAL>
__global__ __launch_bounds__(256) void agg128_kernel(const float* __restrict__ h,
                                                     const int* __restrict__ row_start,
                                                     const int* __restrict__ csr_src,
                                                     const float* __restrict__ csr_w,
                                                     const float* __restrict__ dis,
                                                     const float* __restrict__ bmu,
                                                     const float* __restrict__ blog,
                                                     float* __restrict__ out,
                                                     float* __restrict__ outlog, int M) {
    int wid = threadIdx.x >> 6;
    int lane = threadIdx.x & 63;
    int node = blockIdx.x * 4 + wid;
    if (node >= M) return;
    int half = lane >> 5;
    int c0 = (lane & 31) * 4;

    int s = row_start[node];
    int e = row_start[node + 1];

    float a0 = 0.f, a1 = 0.f, a2 = 0.f, a3 = 0.f;
    int i = s + half;
    for (; i + 2 < e; i += 4) {
        int s0 = csr_src[i];
        int s1 = csr_src[i + 2];
        float w0 = csr_w[i];
        float w1 = csr_w[i + 2];
        float4 v0 = *(const float4*)&h[(size_t)s0 * 128 + c0];
        float4 v1 = *(const float4*)&h[(size_t)s1 * 128 + c0];
        a0 = fmaf(w0, v0.x, a0); a1 = fmaf(w0, v0.y, a1);
        a2 = fmaf(w0, v0.z, a2); a3 = fmaf(w0, v0.w, a3);
        a0 = fmaf(w1, v1.x, a0); a1 = fmaf(w1, v1.y, a1);
        a2 = fmaf(w1, v1.z, a2); a3 = fmaf(w1, v1.w, a3);
    }
    if (i < e) {
        int s0 = csr_src[i];
        float w0 = csr_w[i];
        float4 v0 = *(const float4*)&h[(size_t)s0 * 128 + c0];
        a0 = fmaf(w0, v0.x, a0); a1 = fmaf(w0, v0.y, a1);
        a2 = fmaf(w0, v0.z, a2); a3 = fmaf(w0, v0.w, a3);
    }
    // combine the two half-wave partial sums (lane <-> lane^32)
    a0 += __shfl_xor(a0, 32);
    a1 += __shfl_xor(a1, 32);
    a2 += __shfl_xor(a2, 32);
    a3 += __shfl_xor(a3, 32);

    // self-loop term (added once, after combine)
    float dn = dis[node];
    float sw = dn * dn;
    float4 sv = *(const float4*)&h[(size_t)node * 128 + c0];
    a0 = fmaf(sw, sv.x, a0); a1 = fmaf(sw, sv.y, a1);
    a2 = fmaf(sw, sv.z, a2); a3 = fmaf(sw, sv.w, a3);

    if (half == 0) {
        if constexpr (FINAL) {
            float b0, b1, b2, b3;
            float* yp;
            if (c0 < 64) {
                b0 = bmu[c0]; b1 = bmu[c0 + 1]; b2 = bmu[c0 + 2]; b3 = bmu[c0 + 3];
                yp = out + (size_t)node * 64 + c0;
            } else {
                int c = c0 - 64;
                b0 = blog[c]; b1 = blog[c + 1]; b2 = blog[c + 2]; b3 = blog[c + 3];
                yp = outlog + (size_t)node * 64 + c;
            }
            float4 o;
            o.x = fmaxf(a0 + b0, 0.f);
            o.y = fmaxf(a1 + b1, 0.f);
            o.z = fmaxf(a2 + b2, 0.f);
            o.w = fmaxf(a3 + b3, 0.f);
            *(float4*)yp = o;
        } else {
            *(float4*)&out[(size_t)node * 128 + c0] = make_float4(a0, a1, a2, a3);
        }
    }
}

// ---------------------------------------------------------------------------
// Dual-branch fused GEMM.
//   Y[:, 0:N/2]   = act( X[:, XA:XA+K] @ Wa + ba )
//   Y[:, N/2:N]   = act( X[:, XB:XB+K] @ Wb + bb )
// X is LDXS wide (staged fully in LDS); Wa/Wb are [K, N/2] row-major.
// 256 threads; BM rows/block; each thread: RPT rows x (4 cols branch-a +
// 4 cols branch-b) as two float4 groups. W staged in K-chunks of KCH.
// ---------------------------------------------------------------------------
template <int K, int N, int LDXS, int XA, int XB, int BM, int KCH, bool RELU>
__global__ __launch_bounds__(256) void gemm2_kernel(const float* __restrict__ X,
                                                    const float* __restrict__ Wa,
                                                    const float* __restrict__ Wb,
                                                    const float* __restrict__ ba,
                                                    const float* __restrict__ bb,
                                                    float* __restrict__ Y, int ldy, int M) {
    constexpr int NTX = N / 8;          // threads across cols (8 cols each)
    constexpr int NTY = 256 / NTX;      // thread groups down rows
    constexpr int RPT = BM / NTY;       // rows per thread
    constexpr int XLD = LDXS + 4;
    constexpr int NH = N / 2;
    __shared__ alignas(16) float xs[BM * XLD];
    __shared__ alignas(16) float ws[KCH * N];

    int t = threadIdx.x;
    int row0 = blockIdx.x * BM;

    // stage X tile (float4, zero-fill OOB rows)
    constexpr int KQ = LDXS / 4;
    for (int i = t; i < BM * KQ; i += 256) {
        int r = i / KQ, kq = i % KQ;
        float4 v = make_float4(0.f, 0.f, 0.f, 0.f);
        if (row0 + r < M) v = *(const float4*)&X[(size_t)(row0 + r) * LDXS + 4 * kq];
        *(float4*)&xs[r * XLD + 4 * kq] = v;
    }

    int tx = t % NTX;
    int ty = t / NTX;
    float acc[RPT][8];
    #pragma unroll
    for (int rr = 0; rr < RPT; rr++)
        #pragma unroll
        for (int j = 0; j < 8; j++) acc[rr][j] = 0.f;

    for (int kc = 0; kc < K; kc += KCH) {
        __syncthreads();   // X ready (first iter) / ws safe to overwrite (later)
        constexpr int NQ = N / 4;
        constexpr int HQ = NH / 4;
        for (int i = t; i < KCH * NQ; i += 256) {
            int kk = i / NQ, cq = i % NQ;
            float4 v;
            if (cq < HQ) v = *(const float4*)&Wa[(size_t)(kc + kk) * NH + 4 * cq];
            else         v = *(const float4*)&Wb[(size_t)(kc + kk) * NH + 4 * (cq - HQ)];
            *(float4*)&ws[kk * N + 4 * cq] = v;
        }
        __syncthreads();

        #pragma unroll 4
        for (int kk = 0; kk < KCH; ++kk) {
            int k = kc + kk;
            float4 wa = *(const float4*)&ws[kk * N + tx * 4];
            float4 wb = *(const float4*)&ws[kk * N + NH + tx * 4];
            #pragma unroll
            for (int rr = 0; rr < RPT; rr++) {
                int rbase = (ty * RPT + rr) * XLD;
                float xa = xs[rbase + XA + k];
                acc[rr][0] = fmaf(xa, wa.x, acc[rr][0]);
                acc[rr][1] = fmaf(xa, wa.y, acc[rr][1]);
                acc[rr][2] = fmaf(xa, wa.z, acc[rr][2]);
                acc[rr][3] = fmaf(xa, wa.w, acc[rr][3]);
                float xb;
                if constexpr (XA == XB) xb = xa;
                else xb = xs[rbase + XB + k];
                acc[rr][4] = fmaf(xb, wb.x, acc[rr][4]);
                acc[rr][5] = fmaf(xb, wb.y, acc[rr][5]);
                acc[rr][6] = fmaf(xb, wb.z, acc[rr][6]);
                acc[rr][7] = fmaf(xb, wb.w, acc[rr][7]);
            }
        }
    }

    // epilogue
    int ca = tx * 4;                   // branch-a cols [ca..ca+3], branch-b at NH+ca
    float4 bva = *(const float4*)&ba[ca];
    float4 bvb = *(const float4*)&bb[ca];
    #pragma unroll
    for (int rr = 0; rr < RPT; rr++) {
        int row = row0 + ty * RPT + rr;
        if (row < M) {
            float4 oa, ob;
            oa.x = acc[rr][0] + bva.x; oa.y = acc[rr][1] + bva.y;
            oa.z = acc[rr][2] + bva.z; oa.w = acc[rr][3] + bva.w;
            ob.x = acc[rr][4] + bvb.x; ob.y = acc[rr][5] + bvb.y;
            ob.z = acc[rr][6] + bvb.z; ob.w = acc[rr][7] + bvb.w;
            if constexpr (RELU) {
                oa.x = fmaxf(oa.x, 0.f); oa.y = fmaxf(oa.y, 0.f);
                oa.z = fmaxf(oa.z, 0.f); oa.w = fmaxf(oa.w, 0.f);
                ob.x = fmaxf(ob.x, 0.f); ob.y = fmaxf(ob.y, 0.f);
                ob.z = fmaxf(ob.z, 0.f); ob.w = fmaxf(ob.w, 0.f);
            }
            *(float4*)&Y[(size_t)row * ldy + ca] = oa;
            *(float4*)&Y[(size_t)row * ldy + NH + ca] = ob;
        }
    }
}

extern "C" void kernel_launch(void* const* d_in, const int* in_sizes, int n_in,
                              void* d_out, int out_size, void* d_ws, size_t ws_size,
                              hipStream_t stream) {
    const float* x   = (const float*)d_in[0];
    const int*   ei  = (const int*)d_in[1];
    const float* Wm1 = (const float*)d_in[2];  const float* bm1 = (const float*)d_in[3];
    const float* Wm2 = (const float*)d_in[4];  const float* bm2 = (const float*)d_in[5];
    const float* Wm3 = (const float*)d_in[6];  const float* bm3 = (const float*)d_in[7];
    const float* Wl1 = (const float*)d_in[8];  const float* bl1 = (const float*)d_in[9];
    const float* Wl2 = (const float*)d_in[10]; const float* bl2 = (const float*)d_in[11];
    const float* Wl3 = (const float*)d_in[12]; const float* bl3 = (const float*)d_in[13];
    float* out = (float*)d_out;

    const int M = N_NODES_C;
    const int E = in_sizes[1] / 2;

    char* ws = (char*)d_ws;
    size_t off = 0;
    auto alloc = [&](size_t bytes) {
        size_t o = off;
        off += (bytes + 255) & ~(size_t)255;
        return o;
    };
    int*   flag      = (int*)(ws + alloc(4));
    int*   counts    = (int*)(ws + alloc((size_t)M * 4));
    int*   row_start = (int*)(ws + alloc((size_t)(M + 1) * 4));
    int*   cursor    = (int*)(ws + alloc((size_t)M * 4));
    float* dis       = (float*)(ws + alloc((size_t)M * 4));
    int*   csr_src   = (int*)(ws + alloc((size_t)E * 4));
    float* csr_w     = (float*)(ws + alloc((size_t)E * 4));
    float* bufA      = (float*)(ws + alloc((size_t)M * 256 * 4));
    float* bufB      = (float*)(ws + alloc((size_t)M * 256 * 4));

    hipMemsetAsync(flag, 1, 4, stream);                 // nonzero -> assume int64
    hipMemsetAsync(counts, 0, (size_t)M * 4, stream);

    int ncheck = (E < 2048) ? E : 2048;
    detect_kernel<<<(ncheck + 255) / 256, 256, 0, stream>>>(ei, ncheck, flag);
    count_kernel<<<(E + 255) / 256, 256, 0, stream>>>(ei, E, flag, counts);
    dis_kernel<<<(M + 255) / 256, 256, 0, stream>>>(counts, dis, M);
    scan_kernel<<<1, 1024, 0, stream>>>(counts, row_start, cursor, M);
    fill_kernel<<<(E + 255) / 256, 256, 0, stream>>>(ei, E, flag, dis, cursor, csr_src, csr_w);

    int ablocks = (M + 3) / 4;

    // aggX = A_hat @ x  (pure linear)            x[50000,128] -> bufA[:,0:128]
    agg128_kernel<false><<<ablocks, 256, 0, stream>>>(x, row_start, csr_src, csr_w, dis,
                                                      nullptr, nullptr, bufA, nullptr, M);

    // layer 1: h1 = relu(aggX @ [Wm1|Wl1] + [bm1|bl1]) -> bufB[:,0:128]  (mu64|log64)
    // K=128, N=128, LDXS=128, XA=XB=0, BM=64 (RPT=4), KCH=32
    gemm2_kernel<128, 128, 128, 0, 0, 64, 32, true><<<(M + 63) / 64, 256, 0, stream>>>(
        bufA, Wm1, Wl1, bm1, bl1, bufB, 128, M);

    // aggB = A_hat @ h1 (pure)                   bufB[:,0:128] -> bufA[:,0:128]
    agg128_kernel<false><<<ablocks, 256, 0, stream>>>(bufB, row_start, csr_src, csr_w, dis,
                                                      nullptr, nullptr, bufA, nullptr, M);

    // layer 2 merged: mu = relu(aggB[:,0:64]@Wm2+bm2), log = relu(aggB[:,64:128]@Wl2+bl2)
    // -> bufB[:,0:256] (mu128|log128). K=64, N=256, LDXS=128, XA=0, XB=64, BM=32, KCH=32
    gemm2_kernel<64, 256, 128, 0, 64, 32, 32, true><<<(M + 31) / 32, 256, 0, stream>>>(
        bufA, Wm2, Wl2, bm2, bl2, bufB, 256, M);

    // layer 3 merged (no bias/relu; linear part only):
    // g_mu = bufB[:,0:128]@Wm3, g_log = bufB[:,128:256]@Wl3 -> bufA[:,0:128] (mu64|log64)
    // K=128, N=128, LDXS=256, XA=0, XB=128, BM=32 (RPT=2), KCH=32
    float* zb = (float*)(ws + alloc(64 * 4));
    hipMemsetAsync(zb, 0, 64 * 4, stream);
    gemm2_kernel<128, 128, 256, 0, 128, 32, 32, false><<<(M + 31) / 32, 256, 0, stream>>>(
        bufB, Wm3, Wl3, zb, zb, bufA, 128, M);

    // final aggregation + bias + relu, split mu|log into d_out
    agg128_kernel<true><<<ablocks, 256, 0, stream>>>(bufA, row_start, csr_src, csr_w, dis,
                                                     bm3, bl3, out, out + (size_t)M * 64, M);
}